// Round 12
// baseline (89.644 us; speedup 1.0000x reference)
//
#include <hip/hip_runtime.h>
#include <math.h>

#define NUM_MOE 64
#define DIM 64
#define CH 16            // float4 chunks per row
#define TOK 64           // tokens per tile
#define NW 4             // waves per block
#define ET 8             // experts per inner pass (2 passes per wave)
#define NT 4             // tiles per block (persistent-ish)

typedef float f32x2 __attribute__((ext_vector_type(2)));
typedef float f32x4 __attribute__((ext_vector_type(4)));
typedef float f32x8 __attribute__((ext_vector_type(8)));

// R10 components (42us best: x8 scalar W path, XOR-swizzled LDS, builtin
// fma, zero-fill + single-wave scatter epilogue) restructured as
// persistent-ish blocks: 1024 blocks x 4 tiles, exactly 4 blocks/CU
// resident all kernel (LDS 40960 B), double-buffered x staging so the
// next tile's global loads hide under the current tile's FMA pass 0.
__global__ __launch_bounds__(256)
void moe_router_kernel(const float* __restrict__ x,
                       const float* __restrict__ W,
                       float* __restrict__ out,
                       int ntok) {
    __shared__ f32x4 xs[2][TOK * CH];                // 32768 B
    __shared__ f32x2 pmm[2][NW][TOK];                //  4096 B (m1,m2)
    __shared__ float pzz[2][NW][TOK];                //  2048 B
    __shared__ int   pii[2][NW][TOK];                //  2048 B (i1|i2<<8)
                                                     // total 40960 B -> 4 blk/CU
    const int tid  = threadIdx.x;
    const int lane = tid & 63;
    const int wid  = __builtin_amdgcn_readfirstlane(tid >> 6);
    const long tile0 = (long)blockIdx.x * NT;

    const f32x4* __restrict__ g4 = reinterpret_cast<const f32x4*>(x);
    const f32x8* __restrict__ Wg8 =
        reinterpret_cast<const f32x8*>(W) + (size_t)wid * 16 * (DIM / 8);

    // ---- stage tile 0 loads ----
    f32x4 st[4];
    {
        const long tb = tile0 * TOK;
        #pragma unroll
        for (int j = 0; j < 4; ++j) {
            const int G = tid + j * 256;
            const long tk = tb + (G >> 4);
            st[j] = g4[(tk < ntok) ? (tb * CH + G) : 0];
        }
    }
    // ---- zero-fill this block's 4 output tiles (hidden under staging;
    // B0's vmcnt(0) drain orders zeros before any scatter) ----
    {
        f32x4* __restrict__ ob = reinterpret_cast<f32x4*>(out) + tile0 * TOK * CH;
        const f32x4 z4 = {0.0f, 0.0f, 0.0f, 0.0f};
        #pragma unroll
        for (int jj = 0; jj < 4 * NT; ++jj) {
            const int F = tid + jj * 256;            // coalesced
            if (tile0 * TOK + (F >> 4) < ntok) ob[F] = z4;
        }
    }
    // ---- ds_write tile 0 -> buf 0 ----
    #pragma unroll
    for (int j = 0; j < 4; ++j) {
        const int G  = tid + j * 256;
        const int tk = G >> 4, c = G & 15;
        xs[0][tk * CH + (c ^ (tk & 7))] = st[j];
    }
    asm volatile("s_waitcnt vmcnt(0)" ::: "memory");
    __syncthreads();                                 // B0

    for (int it = 0; it < NT; ++it) {
        const int  c  = it & 1;
        const long tb = (tile0 + it) * TOK;
        const bool have_next = (it + 1 < NT);

        // issue next tile's global loads (complete during pass 0)
        if (have_next) {
            const long tbn = (tile0 + it + 1) * TOK;
            #pragma unroll
            for (int j = 0; j < 4; ++j) {
                const int G = tid + j * 256;
                const long tk = tbn + (G >> 4);
                st[j] = g4[(tk < ntok) ? (tbn * CH + G) : 0];
            }
        }

        float m1 = -INFINITY, m2 = -INFINITY, Zp = 0.0f;
        int   i1 = 0, i2 = 0;

        #pragma unroll
        for (int p = 0; p < 2; ++p) {                // two 8-expert passes
            f32x2 acc[ET];
            #pragma unroll
            for (int e = 0; e < ET; ++e) acc[e] = (f32x2){0.0f, 0.0f};

            #pragma unroll
            for (int k8 = 0; k8 < 8; ++k8) {         // 8-dim groups
                const f32x4 xk0 = xs[c][lane * CH + ((2 * k8) ^ (lane & 7))];
                const f32x4 xk1 = xs[c][lane * CH + ((2 * k8 + 1) ^ (lane & 7))];
                const f32x2 xa = {xk0.x, xk0.y};
                const f32x2 xb = {xk0.z, xk0.w};
                const f32x2 xc = {xk1.x, xk1.y};
                const f32x2 xd = {xk1.z, xk1.w};
                #pragma unroll
                for (int e = 0; e < ET; ++e) {
                    // uniform addr, compile-time offset -> s_load_dwordx8
                    const f32x8 w8 = Wg8[(p * ET + e) * (DIM / 8) + k8];
                    const f32x2 wa = {w8[0], w8[1]};
                    const f32x2 wb = {w8[2], w8[3]};
                    const f32x2 wc = {w8[4], w8[5]};
                    const f32x2 wd = {w8[6], w8[7]};
                    acc[e] = __builtin_elementwise_fma(xa, wa, acc[e]);
                    acc[e] = __builtin_elementwise_fma(xb, wb, acc[e]);
                    acc[e] = __builtin_elementwise_fma(xc, wc, acc[e]);
                    acc[e] = __builtin_elementwise_fma(xd, wd, acc[e]);
                }
            }
            // between passes: park next tile into the other x-buffer.
            // All waves are in iteration `it` (B1_{it-1} passed), readers
            // only touch buf c -> writing buf c^1 is race-free.
            if (p == 0 && have_next) {
                #pragma unroll
                for (int j = 0; j < 4; ++j) {
                    const int G  = tid + j * 256;
                    const int tk = G >> 4, cc = G & 15;
                    xs[c ^ 1][tk * CH + (cc ^ (tk & 7))] = st[j];
                }
            }
            // fold pass into running Z + exact top-2 (strict '>' +
            // ascending order => lowest index wins ties == lax.top_k)
            #pragma unroll
            for (int e = 0; e < ET; ++e) {
                const float v  = acc[e].x + acc[e].y;
                const int   ge = wid * 16 + p * ET + e;
                Zp += __expf(v);                     // logits ~N(0,1): no max-sub
                const bool b1 = v > m1;
                const bool b2 = v > m2;
                i2 = b1 ? i1 : (b2 ? ge : i2);
                m2 = b1 ? m1 : (b2 ? v : m2);
                i1 = b1 ? ge : i1;
                m1 = b1 ? v  : m1;
            }
        }

        // publish partials (parity-buffered: iteration it+1 publishes to
        // part[c^1]; part[c] is republished only at it+2, behind B1_{it+1})
        pmm[c][wid][lane] = (f32x2){m1, m2};
        pzz[c][wid][lane] = Zp;
        pii[c][wid][lane] = i1 | (i2 << 8);
        __syncthreads();                             // B1_it

        // round-robin merger wave: balances the extra epilogue work
        if (wid == (it & (NW - 1))) {
            const int tk = lane;
            f32x2 mm0 = pmm[c][0][tk];
            float M1 = mm0.x, M2 = mm0.y, Z = pzz[c][0][tk];
            int   pk0 = pii[c][0][tk];
            int   I1 = pk0 & 0xFF, I2 = pk0 >> 8;
            #pragma unroll
            for (int w = 1; w < NW; ++w) {
                const f32x2 mmw = pmm[c][w][tk];
                const float b1 = mmw.x, b2 = mmw.y;
                const int   pkw = pii[c][w][tk];
                const int   j1 = pkw & 0xFF, j2 = pkw >> 8;
                Z += pzz[c][w][tk];
                // w-range expert indices all higher -> strict '>' keeps
                // lowest-index-wins tie semantics exactly.
                const bool rep = b1 > M1;
                const float nm2 = rep ? ((b2 > M1) ? b2 : M1) : ((b1 > M2) ? b1 : M2);
                const int   ni2 = rep ? ((b2 > M1) ? j2 : I1) : ((b1 > M2) ? j1 : I2);
                M1 = rep ? b1 : M1;
                I1 = rep ? j1 : I1;
                M2 = nm2;  I2 = ni2;
            }
            // out[I1] = sigmoid((E1-E2)/Z), out[I2] = 1 - out[I1]
            const float E1  = __expf(M1), E2 = __expf(M2);
            const float d12 = (E1 - E2) / Z;
            const float w1  = 1.0f / (1.0f + __expf(-d12));
            const float w2  = 1.0f - w1;
            if (tb + tk < ntok) {
                float* __restrict__ orow = out + (tb + tk) * DIM;
                orow[I1] = w1;                       // zeros landed before B0
                orow[I2] = w2;
            }
        }
    }
}

extern "C" void kernel_launch(void* const* d_in, const int* in_sizes, int n_in,
                              void* d_out, int out_size, void* d_ws, size_t ws_size,
                              hipStream_t stream) {
    const float* x = (const float*)d_in[0];
    const float* W = (const float*)d_in[1];
    float* out = (float*)d_out;
    int ntok = in_sizes[0] / DIM;                    // 262144

    int tiles  = (ntok + TOK - 1) / TOK;             // 4096
    int blocks = (tiles + NT - 1) / NT;              // 1024 = 4 blocks/CU
    moe_router_kernel<<<blocks, 256, 0, stream>>>(x, W, out, ntok);
}

// Round 13
// 46.246 us; speedup vs baseline: 1.9384x; 1.9384x over previous
//
#include <hip/hip_runtime.h>
#include <math.h>

#define NUM_MOE 64
#define DIM 64
#define CH 16            // float4 chunks per row
#define TOK 128          // tokens per block (2 per lane)
#define NW 4             // waves per block
#define ET 8             // experts per inner pass (2 passes per wave)

typedef float f32x2 __attribute__((ext_vector_type(2)));
typedef float f32x4 __attribute__((ext_vector_type(4)));
typedef float f32x8 __attribute__((ext_vector_type(8)));

// R10 (42us best) with ONE variable changed: 128 tokens per block, each
// lane owning tokens {lane, lane+64} with two accumulator sets. Each W
// s_load_dwordx8 now feeds 16 FMA-pairs (was 8) -> chip-wide scalar-pipe
// traffic halves (2.1M -> 1.05M s_loads); barriers/merge per token halve.
// R12's persistent/double-buffer structure is fully reverted (it added
// ~29us of VALU busy-time; occupancy was never cap-limited).
__global__ __launch_bounds__(256)
void moe_router_kernel(const float* __restrict__ x,
                       const float* __restrict__ W,
                       float* __restrict__ out,
                       int ntok) {
    __shared__ f32x4 xs[TOK * CH];                   // 32768 B
    __shared__ f32x2 pmm[NW][TOK];                   //  4096 B (m1,m2)
    __shared__ float pzz[NW][TOK];                   //  2048 B
    __shared__ int   pii[NW][TOK];                   //  2048 B (i1|i2<<8)
                                                     // total 40960 B -> 4 blk/CU
    const int tid    = threadIdx.x;
    const long tbase = (long)blockIdx.x * TOK;

    // ---- stage x (coalesced loads -> contiguous-permuted LDS writes) ----
    {
        const f32x4* __restrict__ g4 = reinterpret_cast<const f32x4*>(x) + tbase * CH;
        #pragma unroll
        for (int j = 0; j < 8; ++j) {
            const int G  = tid + j * 256;            // 0..2047, coalesced read
            const int tk = G >> 4;                   // token in block
            const int c  = G & 15;                   // chunk
            const int Gc = (tbase + tk < ntok) ? G : (G & 15);  // tail clamp
            xs[tk * CH + (c ^ (tk & 7))] = g4[Gc];   // canonical write pattern
        }
    }
    // ---- zero-fill output tile now; latency hides under compute. The
    // pre-compute barrier drains vmcnt -> zeros land before the scatter. ----
    {
        f32x4* __restrict__ ob = reinterpret_cast<f32x4*>(out) + tbase * CH;
        const f32x4 z4 = {0.0f, 0.0f, 0.0f, 0.0f};
        #pragma unroll
        for (int j = 0; j < 8; ++j) {
            const int F = tid + j * 256;             // 0..2047, coalesced
            if (tbase + (F >> 4) < ntok) ob[F] = z4;
        }
    }
    __syncthreads();

    // ---- compute: wave wid owns experts [wid*16, wid*16+16) for 128 tok ----
    const int lane = tid & 63;                       // token A; token B = +64
    const int wid  = __builtin_amdgcn_readfirstlane(tid >> 6);
    const f32x8* __restrict__ Wg8 =
        reinterpret_cast<const f32x8*>(W) + (size_t)wid * 16 * (DIM / 8);

    float m1A = -INFINITY, m2A = -INFINITY, ZpA = 0.0f;
    float m1B = -INFINITY, m2B = -INFINITY, ZpB = 0.0f;
    int   i1A = 0, i2A = 0, i1B = 0, i2B = 0;

    #pragma unroll
    for (int p = 0; p < 2; ++p) {                    // two 8-expert passes
        f32x2 accA[ET], accB[ET];
        #pragma unroll
        for (int e = 0; e < ET; ++e) {
            accA[e] = (f32x2){0.0f, 0.0f};
            accB[e] = (f32x2){0.0f, 0.0f};
        }

        #pragma unroll
        for (int k8 = 0; k8 < 8; ++k8) {             // 8-dim groups
            const int sw0 = (2 * k8) ^ (lane & 7), sw1 = (2 * k8 + 1) ^ (lane & 7);
            const f32x4 a0 = xs[lane * CH + sw0];
            const f32x4 a1 = xs[lane * CH + sw1];
            const f32x4 b0 = xs[(lane + 64) * CH + sw0];
            const f32x4 b1 = xs[(lane + 64) * CH + sw1];
            const f32x2 xaA = {a0.x, a0.y}, xbA = {a0.z, a0.w};
            const f32x2 xcA = {a1.x, a1.y}, xdA = {a1.z, a1.w};
            const f32x2 xaB = {b0.x, b0.y}, xbB = {b0.z, b0.w};
            const f32x2 xcB = {b1.x, b1.y}, xdB = {b1.z, b1.w};
            #pragma unroll
            for (int e = 0; e < ET; ++e) {
                // uniform addr, compile-time offset -> one s_load_dwordx8
                // now feeding 16 FMA-pairs (2 tokens)
                const f32x8 w8 = Wg8[(p * ET + e) * (DIM / 8) + k8];
                const f32x2 wa = {w8[0], w8[1]};
                const f32x2 wb = {w8[2], w8[3]};
                const f32x2 wc = {w8[4], w8[5]};
                const f32x2 wd = {w8[6], w8[7]};
                accA[e] = __builtin_elementwise_fma(xaA, wa, accA[e]);
                accA[e] = __builtin_elementwise_fma(xbA, wb, accA[e]);
                accA[e] = __builtin_elementwise_fma(xcA, wc, accA[e]);
                accA[e] = __builtin_elementwise_fma(xdA, wd, accA[e]);
                accB[e] = __builtin_elementwise_fma(xaB, wa, accB[e]);
                accB[e] = __builtin_elementwise_fma(xbB, wb, accB[e]);
                accB[e] = __builtin_elementwise_fma(xcB, wc, accB[e]);
                accB[e] = __builtin_elementwise_fma(xdB, wd, accB[e]);
            }
        }
        // fold pass into running Z + exact top-2 (strict '>' + ascending
        // order => lowest index wins ties, matching lax.top_k)
        #pragma unroll
        for (int e = 0; e < ET; ++e) {
            const int ge = wid * 16 + p * ET + e;
            {
                const float v = accA[e].x + accA[e].y;
                ZpA += __expf(v);                    // logits ~N(0,1): no max-sub
                const bool b1 = v > m1A;
                const bool b2 = v > m2A;
                i2A = b1 ? i1A : (b2 ? ge : i2A);
                m2A = b1 ? m1A : (b2 ? v : m2A);
                i1A = b1 ? ge : i1A;
                m1A = b1 ? v  : m1A;
            }
            {
                const float v = accB[e].x + accB[e].y;
                ZpB += __expf(v);
                const bool b1 = v > m1B;
                const bool b2 = v > m2B;
                i2B = b1 ? i1B : (b2 ? ge : i2B);
                m2B = b1 ? m1B : (b2 ? v : m2B);
                i1B = b1 ? ge : i1B;
                m1B = b1 ? v  : m1B;
            }
        }
    }

    // ---- publish per-wave partials (disjoint, ascending expert ranges) ----
    pmm[wid][lane]      = (f32x2){m1A, m2A};
    pzz[wid][lane]      = ZpA;
    pii[wid][lane]      = i1A | (i2A << 8);
    pmm[wid][lane + 64] = (f32x2){m1B, m2B};
    pzz[wid][lane + 64] = ZpB;
    pii[wid][lane + 64] = i1B | (i2B << 8);
    __syncthreads();

    // ---- waves 0-1 merge and scatter 2 dwords per token ----
    if (tid < TOK) {
        const int tk = tid;                          // one token per lane
        f32x2 mm0 = pmm[0][tk];
        float M1 = mm0.x, M2 = mm0.y, Z = pzz[0][tk];
        int   pk0 = pii[0][tk];
        int   I1 = pk0 & 0xFF, I2 = pk0 >> 8;
        #pragma unroll
        for (int w = 1; w < NW; ++w) {
            const f32x2 mmw = pmm[w][tk];
            const float b1 = mmw.x, b2 = mmw.y;
            const int   pkw = pii[w][tk];
            const int   j1 = pkw & 0xFF, j2 = pkw >> 8;
            Z += pzz[w][tk];
            // w-range expert indices all higher than current -> strict '>'
            // keeps lowest-index-wins tie semantics exactly.
            const bool rep = b1 > M1;
            const float nm2 = rep ? ((b2 > M1) ? b2 : M1) : ((b1 > M2) ? b1 : M2);
            const int   ni2 = rep ? ((b2 > M1) ? j2 : I1) : ((b1 > M2) ? j1 : I2);
            M1 = rep ? b1 : M1;
            I1 = rep ? j1 : I1;
            M2 = nm2;  I2 = ni2;
        }

        // out[I1] = sigmoid((E1-E2)/Z), out[I2] = 1 - out[I1]
        const float E1  = __expf(M1), E2 = __expf(M2);
        const float d12 = (E1 - E2) / Z;
        const float w1  = 1.0f / (1.0f + __expf(-d12));
        const float w2  = 1.0f - w1;

        if (tbase + tk < ntok) {
            float* __restrict__ orow = out + (tbase + tk) * DIM;
            orow[I1] = w1;                           // zeros landed (barrier
            orow[I2] = w2;                           // drained vmcnt)
        }
    }
}

extern "C" void kernel_launch(void* const* d_in, const int* in_sizes, int n_in,
                              void* d_out, int out_size, void* d_ws, size_t ws_size,
                              hipStream_t stream) {
    const float* x = (const float*)d_in[0];
    const float* W = (const float*)d_in[1];
    float* out = (float*)d_out;
    int ntok = in_sizes[0] / DIM;                    // 262144

    int blocks = (ntok + TOK - 1) / TOK;             // 2048
    moe_router_kernel<<<blocks, 256, 0, stream>>>(x, W, out, ntok);
}